// Round 2
// baseline (732.376 us; speedup 1.0000x reference)
//
#include <hip/hip_runtime.h>
#include <hip/hip_bf16.h>
#include <stdint.h>

// Problem dims (fixed by reference)
#define T_LEN 128
#define B_SZ  256
#define D_IN  1024
#define H_DIM 1024
#define NQ    8
#define VOCAB 32000
#define TAGS  1024

typedef __attribute__((ext_vector_type(8))) short short8;   // 8 bf16 (4 VGPRs)
typedef __attribute__((ext_vector_type(4))) float f32x4;
typedef __attribute__((ext_vector_type(2))) float v2f;      // -> v_pk_fma_f32

// ---------- helpers ----------
__device__ __forceinline__ unsigned short f2bf_bits(float x) {
    __hip_bfloat16 h = __float2bfloat16(x);
    unsigned short u; __builtin_memcpy(&u, &h, 2); return u;
}
__device__ __forceinline__ uint32_t pack_bf2(float a, float b) {
    return (uint32_t)f2bf_bits(a) | ((uint32_t)f2bf_bits(b) << 16);
}
__device__ __forceinline__ float2 unpack_bf2(uint32_t u) {
    float2 r;
    r.x = __uint_as_float(u << 16);
    r.y = __uint_as_float(u & 0xffff0000u);
    return r;
}
__device__ __forceinline__ v2f v2fma(v2f a, v2f b, v2f c) {
#if __has_builtin(__builtin_elementwise_fma)
    return __builtin_elementwise_fma(a, b, c);
#else
    c.x = fmaf(a.x, b.x, c.x); c.y = fmaf(a.y, b.y, c.y); return c;
#endif
}
__device__ __forceinline__ float sigmoid_f(float x) {
    return 1.f / (1.f + __expf(-x));
}
__device__ __forceinline__ float tanh_f(float x) {
    return 1.f - 2.f / (__expf(2.f * x) + 1.f);   // inf-safe
}
__device__ __forceinline__ void gload_lds16(void* lds_base, const void* gptr) {
    __builtin_amdgcn_global_load_lds(
        (__attribute__((address_space(1))) const void*)gptr,
        (__attribute__((address_space(3))) void*)lds_base,
        16, 0, 0);
}

// ---------- K0: W_tag (K x N fp32) -> WtT (N x K bf16) ----------
__global__ __launch_bounds__(256) void k_wt_transpose(const float* __restrict__ W,
                                                      __hip_bfloat16* __restrict__ WtT) {
    __shared__ float tile[32][33];
    const int kb = blockIdx.x * 32, nb = blockIdx.y * 32;
    const int r = threadIdx.x >> 5, c = threadIdx.x & 31;
#pragma unroll
    for (int i = 0; i < 4; ++i)
        tile[r + 8 * i][c] = W[(size_t)(kb + r + 8 * i) * TAGS + nb + c];
    __syncthreads();
#pragma unroll
    for (int i = 0; i < 4; ++i)
        WtT[(size_t)(nb + r + 8 * i) * H_DIM + kb + c] = __float2bfloat16(tile[c][r + 8 * i]);
}

// ---------- K2: recurrent QLSTM. one block per batch element ----------
// 2 barriers/step: phase1 (pk_fma dot) -> B1 -> per-wave redundant reduce+cos
// -> wave-private qs (same-wave DS ordering, no barrier) -> phase2+gates -> B2
__global__ __launch_bounds__(1024) void k_qlstm(
    const int* __restrict__ sent, const float* __restrict__ emb,
    const float* __restrict__ Wg, const float* __restrict__ bg,
    const float* __restrict__ theta, const float* __restrict__ Wp,
    const float* __restrict__ bp, __hip_bfloat16* __restrict__ hb)
{
    __shared__ float comb[2048];      // [0..1023]=x_t, [1024..2047]=h_{t-1}
    __shared__ float red[32 * 17];    // partials: [o][wave], stride 17 (bank-safe)
    __shared__ float qs_w[16 * 32];   // per-wave private cos() copies
    __shared__ int   sw[T_LEN];       // this batch's token ids

    const int tid  = threadIdx.x;
    const int b    = blockIdx.x;
    const int o    = tid & 31;        // output index (g*8+q)
    const int s    = tid >> 5;        // k-slice 0..31 (64 elems each)
    const int g    = o >> 3, q = o & 7;
    const int lane = tid & 63, wv = tid >> 6;

    // phase-1 weights: Wg[g][c][q] for c in [s*64, s*64+64), fp32 pairs (pk_fma)
    v2f wgv[32];
#pragma unroll
    for (int j = 0; j < 32; ++j) {
        const int c0 = s * 64 + 2 * j;
        wgv[j].x = Wg[((size_t)g * 2048 + c0) * 8 + q];
        wgv[j].y = Wg[((size_t)g * 2048 + c0 + 1) * 8 + q];
    }
    // phase-2 weights: Wp[g][qq][h=tid], bf16-packed pairs over qq (register thrift)
    uint32_t wp2[16];
#pragma unroll
    for (int j = 0; j < 16; ++j) {
        const int gg = j >> 2, jj = j & 3;
        float a = Wp[(size_t)(gg * 8 + 2 * jj) * H_DIM + tid];
        float bb = Wp[(size_t)(gg * 8 + 2 * jj + 1) * H_DIM + tid];
        wp2[j] = pack_bf2(a, bb);
    }
    float bpv[4];
#pragma unroll
    for (int gg = 0; gg < 4; ++gg) bpv[gg] = bp[gg * H_DIM + tid];
    const float bgt = bg[o] + theta[o];

    float cx = 0.f;
    comb[1024 + tid] = 0.f;                      // h_{-1} = 0
    if (tid < T_LEN) sw[tid] = sent[tid * B_SZ + b];
    __syncthreads();
    comb[tid] = emb[(size_t)sw[0] * D_IN + tid];
    __syncthreads();

    for (int t = 0; t < T_LEN; ++t) {
        // prefetch next x (independent; hidden under phase1)
        const int tn = (t + 1 < T_LEN) ? (t + 1) : (T_LEN - 1);
        const float xnext = emb[(size_t)sw[tn] * D_IN + tid];

        // ---- phase 1: raw[o] partial over k-slice s (packed fp32 FMA) ----
        v2f a0 = (v2f){0.f, 0.f}, a1 = (v2f){0.f, 0.f};
        const float4* c4 = (const float4*)comb;
#pragma unroll
        for (int i = 0; i < 16; ++i) {
            float4 v = c4[s * 16 + i];            // broadcast within half-wave: 0 conflicts
            a0 = v2fma(wgv[2 * i],     (v2f){v.x, v.y}, a0);
            a1 = v2fma(wgv[2 * i + 1], (v2f){v.z, v.w}, a1);
        }
        float acc = (a0.x + a1.x) + (a0.y + a1.y);
        acc += __shfl_xor(acc, 32, 64);           // fold the wave's two k-slices
        if (lane < 32) red[o * 17 + wv] = acc;
        __syncthreads();                          // B1 (phase1 reads of comb done)

        comb[tid] = xnext;                        // stage x_{t+1}

        // ---- per-wave redundant cross-wave reduce + quantum layer ----
        float r0 = 0.f, r1 = 0.f, r2 = 0.f, r3 = 0.f;
#pragma unroll
        for (int w = 0; w < 4; ++w) {             // 16 conflict-free b32 reads
            r0 += red[o * 17 + 4 * w + 0];
            r1 += red[o * 17 + 4 * w + 1];
            r2 += red[o * 17 + 4 * w + 2];
            r3 += red[o * 17 + 4 * w + 3];
        }
        const float qv = __cosf(((r0 + r1) + (r2 + r3)) + bgt);
        if (lane < 32) qs_w[wv * 32 + lane] = qv; // wave-private copy
        // same-wave DS ordering: reads below see the writes above, no barrier

        // ---- phase 2: projection + gates, one h per thread ----
        const float4* q4 = (const float4*)&qs_w[wv * 32];
        float pj[4];
#pragma unroll
        for (int gg = 0; gg < 4; ++gg) {
            float4 u = q4[2 * gg], v = q4[2 * gg + 1];
            float2 w0 = unpack_bf2(wp2[gg * 4 + 0]);
            float2 w1 = unpack_bf2(wp2[gg * 4 + 1]);
            float2 w2 = unpack_bf2(wp2[gg * 4 + 2]);
            float2 w3 = unpack_bf2(wp2[gg * 4 + 3]);
            pj[gg] = bpv[gg]
                   + u.x * w0.x + u.y * w0.y + u.z * w1.x + u.w * w1.y
                   + v.x * w2.x + v.y * w2.y + v.z * w3.x + v.w * w3.y;
        }
        const float f_ = sigmoid_f(pj[0]);
        const float i_ = sigmoid_f(pj[1]);
        const float g_ = tanh_f(pj[2]);
        const float o_ = sigmoid_f(pj[3]);
        cx = f_ * cx + i_ * g_;
        const float hv = o_ * tanh_f(cx);
        comb[1024 + tid] = hv;
        hb[((size_t)t * B_SZ + b) * H_DIM + tid] = __float2bfloat16(hv);
        __syncthreads();                          // B2 (comb/red safe for next step)
    }
}

// ---------- K3: tag GEMM  C(32768x1024 f32) = Hb(bf16) x W_tag(bf16) ----------
__global__ __launch_bounds__(256) void k_tag_gemm(const __hip_bfloat16* __restrict__ Hb,
                                                  const __hip_bfloat16* __restrict__ WtT,
                                                  float* __restrict__ out)
{
    __shared__ short As[128 * 32];   // [row][k] bf16, unpadded (global_load_lds layout)
    __shared__ short Bs[128 * 32];   // [n][k]   bf16
    const int m0 = blockIdx.x * 128, n0 = blockIdx.y * 128;
    const int tid = threadIdx.x, lane = tid & 63, wid = tid >> 6;
    const int wm = (wid & 1) * 64, wn = (wid >> 1) * 64;
    const int mrow = lane & 15, quad = lane >> 4;

    const short* Hs = (const short*)Hb;
    const short* Ws = (const short*)WtT;

    f32x4 acc[4][4];
#pragma unroll
    for (int mi = 0; mi < 4; ++mi)
#pragma unroll
        for (int ni = 0; ni < 4; ++ni)
            acc[mi][ni] = (f32x4){0.f, 0.f, 0.f, 0.f};

    for (int kt = 0; kt < 32; ++kt) {
        const int k0 = kt * 32;
        __syncthreads();
#pragma unroll
        for (int ch = 0; ch < 2; ++ch) {
            const int chunk = wid + ch * 4;
            const int row = chunk * 16 + (lane >> 2);
            const int kc = (lane & 3) * 8;
            gload_lds16(&As[chunk * 512], &Hs[(size_t)(m0 + row) * H_DIM + k0 + kc]);
            gload_lds16(&Bs[chunk * 512], &Ws[(size_t)(n0 + row) * H_DIM + k0 + kc]);
        }
        __syncthreads();

        short8 afr[4], bfr[4];
#pragma unroll
        for (int mi = 0; mi < 4; ++mi)
            afr[mi] = *(const short8*)&As[(wm + mi * 16 + mrow) * 32 + quad * 8];
#pragma unroll
        for (int ni = 0; ni < 4; ++ni)
            bfr[ni] = *(const short8*)&Bs[(wn + ni * 16 + mrow) * 32 + quad * 8];
#pragma unroll
        for (int mi = 0; mi < 4; ++mi)
#pragma unroll
            for (int ni = 0; ni < 4; ++ni)
                acc[mi][ni] = __builtin_amdgcn_mfma_f32_16x16x32_bf16(
                    afr[mi], bfr[ni], acc[mi][ni], 0, 0, 0);
    }

    // epilogue (no bias: b_tag is constant along the softmax axis -> cancels)
#pragma unroll
    for (int mi = 0; mi < 4; ++mi)
#pragma unroll
        for (int ni = 0; ni < 4; ++ni)
#pragma unroll
            for (int r = 0; r < 4; ++r) {
                const int grow = m0 + wm + mi * 16 + quad * 4 + r;
                const int gcol = n0 + wn + ni * 16 + mrow;
                out[(size_t)grow * TAGS + gcol] = acc[mi][ni][r];
            }
}

// ---------- K4: log_softmax over batch axis, online stats (3 passes total) ----------
__global__ __launch_bounds__(256) void k_logsoftmax(float* __restrict__ out) {
    const int t = blockIdx.x;
    const int n2 = (blockIdx.y * 256 + threadIdx.x) * 2;   // 2 columns per thread
    float* base = out + (size_t)t * B_SZ * TAGS + n2;
    float mx = -1e30f, my = -1e30f, sx = 0.f, sy = 0.f;
    for (int b = 0; b < B_SZ; ++b) {
        float2 x = *(const float2*)&base[(size_t)b * TAGS];
        float nmx = fmaxf(mx, x.x), nmy = fmaxf(my, x.y);
        sx = sx * __expf(mx - nmx) + __expf(x.x - nmx);
        sy = sy * __expf(my - nmy) + __expf(x.y - nmy);
        mx = nmx; my = nmy;
    }
    const float lx = mx + __logf(sx), ly = my + __logf(sy);
    for (int b = 0; b < B_SZ; ++b) {
        float2 x = *(const float2*)&base[(size_t)b * TAGS];
        x.x -= lx; x.y -= ly;
        *(float2*)&base[(size_t)b * TAGS] = x;
    }
}

extern "C" void kernel_launch(void* const* d_in, const int* in_sizes, int n_in,
                              void* d_out, int out_size, void* d_ws, size_t ws_size,
                              hipStream_t stream) {
    (void)in_sizes; (void)n_in; (void)out_size; (void)ws_size;
    const int*   sent  = (const int*)d_in[0];
    const float* emb   = (const float*)d_in[1];
    const float* Wg    = (const float*)d_in[2];
    const float* bg    = (const float*)d_in[3];
    const float* theta = (const float*)d_in[4];
    const float* Wp    = (const float*)d_in[5];
    const float* bp    = (const float*)d_in[6];
    const float* Wt    = (const float*)d_in[7];
    // d_in[8] = b_tag: constant along the softmax (batch) axis -> cancels exactly.
    float* out = (float*)d_out;

    __hip_bfloat16* hb  = (__hip_bfloat16*)d_ws;                                     // 64 MB
    __hip_bfloat16* WtT = (__hip_bfloat16*)((char*)d_ws + (size_t)64 * 1024 * 1024); // 2 MB

    k_wt_transpose<<<dim3(32, 32), 256, 0, stream>>>(Wt, WtT);
    k_qlstm<<<dim3(B_SZ), 1024, 0, stream>>>(sent, emb, Wg, bg, theta, Wp, bp, hb);
    k_tag_gemm<<<dim3(256, 8), 256, 0, stream>>>(hb, WtT, out);
    k_logsoftmax<<<dim3(T_LEN, 2), 256, 0, stream>>>(out);
}